// Round 6
// baseline (388.485 us; speedup 1.0000x reference)
//
#include <hip/hip_runtime.h>

// Problem constants
#define B_   8
#define N_   1024
#define C_   1024
#define H_   16
#define P_   64
#define D_   64
#define MKV  1088      // P_ + N_
#define ROWS 8192      // B_*N_

typedef float f32x4 __attribute__((ext_vector_type(4)));
typedef __bf16 bf16x8 __attribute__((ext_vector_type(8)));
typedef unsigned short u16x8 __attribute__((ext_vector_type(8)));
typedef unsigned short u16x4 __attribute__((ext_vector_type(4)));

__device__ __forceinline__ unsigned short f2bf(float f) {
  unsigned u = __float_as_uint(f);
  u += 0x7fffu + ((u >> 16) & 1u);   // round-to-nearest-even
  return (unsigned short)(u >> 16);
}

#define GLDS16(g, l)                                                          \
  __builtin_amdgcn_global_load_lds(                                           \
      (const __attribute__((address_space(1))) void*)(g),                     \
      (__attribute__((address_space(3))) void*)(l), 16, 0, 0)

// ---------------------------------------------------------------------------
__global__ __launch_bounds__(256) void cast_bf16_k(
    const float* __restrict__ in, unsigned short* __restrict__ out, int n8) {
  int i = blockIdx.x * 256 + threadIdx.x;
  if (i >= n8) return;
  const float4 a = ((const float4*)in)[i * 2];
  const float4 c = ((const float4*)in)[i * 2 + 1];
  u16x8 o;
  o[0] = f2bf(a.x); o[1] = f2bf(a.y); o[2] = f2bf(a.z); o[3] = f2bf(a.w);
  o[4] = f2bf(c.x); o[5] = f2bf(c.y); o[6] = f2bf(c.z); o[7] = f2bf(c.w);
  *(u16x8*)(out + (size_t)i * 8) = o;
}

// ---------------------------------------------------------------------------
__global__ __launch_bounds__(256) void ln_bf16(
    const float* __restrict__ x, const float* __restrict__ g,
    const float* __restrict__ b, unsigned short* __restrict__ out) {
  const int row = blockIdx.x, t = threadIdx.x;
  const float4 v = ((const float4*)(x + (size_t)row * 1024))[t];
  float s  = v.x + v.y + v.z + v.w;
  float s2 = v.x * v.x + v.y * v.y + v.z * v.z + v.w * v.w;
#pragma unroll
  for (int m = 1; m < 64; m <<= 1) {
    s  += __shfl_xor(s, m);
    s2 += __shfl_xor(s2, m);
  }
  __shared__ float red[8];
  if ((t & 63) == 0) { red[t >> 6] = s; red[4 + (t >> 6)] = s2; }
  __syncthreads();
  s  = red[0] + red[1] + red[2] + red[3];
  s2 = red[4] + red[5] + red[6] + red[7];
  const float mu = s * (1.0f / 1024.0f);
  const float rs = rsqrtf(s2 * (1.0f / 1024.0f) - mu * mu + 1e-5f);
  const float4 gv = ((const float4*)g)[t];
  const float4 bv = ((const float4*)b)[t];
  u16x4 o;
  o[0] = f2bf((v.x - mu) * rs * gv.x + bv.x);
  o[1] = f2bf((v.y - mu) * rs * gv.y + bv.y);
  o[2] = f2bf((v.z - mu) * rs * gv.z + bv.z);
  o[3] = f2bf((v.w - mu) * rs * gv.w + bv.w);
  *(u16x4*)(out + (size_t)row * 1024 + t * 4) = o;
}

// ---------------------------------------------------------------------------
__global__ __launch_bounds__(256) void prefix_fill(
    const float* __restrict__ pk, const float* __restrict__ pv,
    unsigned short* __restrict__ Kb, unsigned short* __restrict__ Vb) {
  int i = blockIdx.x * 256 + threadIdx.x;
  int c8 = i & 127, bp = i >> 7;
  int b = bp >> 6, p = bp & 63;
  int c = c8 << 3, h = c >> 6, d = c & 63;
  size_t sidx = (size_t)bp * 1024 + c;
  size_t didx = (((size_t)(b * 16 + h)) * MKV + p) * 64 + d;
  float4 a = *(const float4*)(pk + sidx);
  float4 a2 = *(const float4*)(pk + sidx + 4);
  u16x8 o;
  o[0] = f2bf(a.x);  o[1] = f2bf(a.y);  o[2] = f2bf(a.z);  o[3] = f2bf(a.w);
  o[4] = f2bf(a2.x); o[5] = f2bf(a2.y); o[6] = f2bf(a2.z); o[7] = f2bf(a2.w);
  *(u16x8*)(Kb + didx) = o;
  a = *(const float4*)(pv + sidx);
  a2 = *(const float4*)(pv + sidx + 4);
  o[0] = f2bf(a.x);  o[1] = f2bf(a.y);  o[2] = f2bf(a.z);  o[3] = f2bf(a.w);
  o[4] = f2bf(a2.x); o[5] = f2bf(a2.y); o[6] = f2bf(a2.z); o[7] = f2bf(a2.w);
  *(u16x8*)(Vb + didx) = o;
}

// ---------------------------------------------------------------------------
__global__ __launch_bounds__(256) void transpose_v(
    const unsigned short* __restrict__ Vb, unsigned short* __restrict__ Vt) {
  __shared__ __align__(16) unsigned short Ts[64 * 66];
  const int kt = blockIdx.x, bh = blockIdx.y;
  const int t = threadIdx.x;
  const unsigned short* src = Vb + ((size_t)bh * MKV + kt * 64) * 64;
#pragma unroll
  for (int rnd = 0; rnd < 2; rnd++) {
    int chunk = rnd * 256 + t;
    int mr = chunk >> 3, d0 = (chunk & 7) << 3;
    u16x8 a = *(const u16x8*)(src + mr * 64 + d0);
#pragma unroll
    for (int j = 0; j < 8; j += 2)
      *(unsigned*)&Ts[mr * 66 + d0 + j] = (unsigned)a[j] | ((unsigned)a[j + 1] << 16);
  }
  __syncthreads();
#pragma unroll
  for (int rnd = 0; rnd < 2; rnd++) {
    int chunk = rnd * 256 + t;
    int dr = chunk >> 3, m0 = (chunk & 7) << 3;
    u16x8 o;
#pragma unroll
    for (int j = 0; j < 8; j++) o[j] = Ts[(m0 + j) * 66 + dr];
    *(u16x8*)(Vt + ((size_t)bh * 64 + dr) * MKV + kt * 64 + m0) = o;
  }
}

// ---------------------------------------------------------------------------
// GEMM "gemmw": C[M,Nd] = A[M,K] @ Bw[Nd,K]^T, bf16 in, fp32 accum.
// R4-verified 3-stage schedule, scaled: BM=256, BK=64, 512 thr.
//   BN_=256: waves 2x4, per-wave 128x64; LDS = A 3x32KB + B 2x32KB = 160KB.
//   BN_=128: waves 4x2, per-wave 64x64;  LDS = A 3x32KB + B 2x16KB = 128KB.
// A ring of 3 (staged s+2 ahead), B ring of 2 (staged s+1 ahead), constant
// counted vmcnt(4)=A(s+1) loads (T4); one barrier/tile; XOR-swizzle (T2);
// bijective XCD swizzle (T1). Same liveness proof as R4's gemm3s.
template <int EPI, int BN_>
__global__ __launch_bounds__(512, 2) void gemmw(
    const unsigned short* __restrict__ A, const unsigned short* __restrict__ Bw,
    const float* __restrict__ bias, const float* __restrict__ resid,
    float* __restrict__ outf, unsigned short* __restrict__ outb,
    unsigned short* __restrict__ qout, unsigned short* __restrict__ kout,
    unsigned short* __restrict__ vout, int Ndim, int Kdim) {
  constexpr int WN   = BN_ / 64;              // waves along N: 4 or 2
  constexpr int WMT  = (WN == 4) ? 128 : 64;  // per-wave M
  constexpr int MREP = WMT / 16;              // 8 or 4
  constexpr int ABUF = 32768;                 // 256 rows x 128B
  constexpr int BBUF = BN_ * 128;
  constexpr int BOFF = 3 * ABUF;              // 98304
  extern __shared__ __align__(16) char smem[];
  const int t = threadIdx.x;
  const int w = t >> 6, l = t & 63;
  const int wr = w / WN, wc = w % WN;
  const int q4 = l >> 4, r15 = l & 15;
  // T1: bijective XCD swizzle (nwg % 8 == 0 for all grids used)
  const int fid = (int)blockIdx.y * 32 + blockIdx.x;
  const int nwg = (int)gridDim.y * 32;
  const int id2 = (fid & 7) * (nwg >> 3) + (fid >> 3);
  const int bm = id2 & 31, bn = id2 >> 5;
  const int NS = Kdim >> 6;
  // ---- staging (T2: pre-swizzled source, linear LDS dest = wavebase+16*lane)
  const int sr = t >> 3, scolb = (t & 7) << 4;
  const int sswz = scolb ^ ((sr & 7) << 4);
  const size_t rb = (size_t)Kdim * 2;
  const char* As0 = (const char*)A + (size_t)(bm * 256 + sr) * rb + sswz;
  const char* Bs0 = (const char*)Bw + (size_t)(bn * BN_ + sr) * rb + sswz;
  char* Adst = smem + t * 16;
  char* Bdst = smem + BOFF + t * 16;
#define STG_A(s_, st_) {                                                      \
    const int ko = (s_) << 7;                                                 \
    GLDS16(As0 + ko,            Adst + (st_) * ABUF);                         \
    GLDS16(As0 + 64 * rb + ko,  Adst + (st_) * ABUF + 8192);                  \
    GLDS16(As0 + 128 * rb + ko, Adst + (st_) * ABUF + 16384);                 \
    GLDS16(As0 + 192 * rb + ko, Adst + (st_) * ABUF + 24576); }
#define STG_B(s_, sb_) {                                                      \
    const int ko = (s_) << 7;                                                 \
    GLDS16(Bs0 + ko,           Bdst + (sb_) * BBUF);                          \
    GLDS16(Bs0 + 64 * rb + ko, Bdst + (sb_) * BBUF + 8192);                   \
    if (BN_ == 256) {                                                         \
      GLDS16(Bs0 + 128 * rb + ko, Bdst + (sb_) * BBUF + 16384);               \
      GLDS16(Bs0 + 192 * rb + ko, Bdst + (sb_) * BBUF + 24576); } }
  // ---- fragment read bases (swizzled ds_read)
  const int rx = (r15 & 7) << 4;
  const int c0 = (q4 << 4) ^ rx;
  const int c1 = c0 ^ 64;
  const char* arow = smem + (wr * WMT + r15) * 128;
  const char* brow = smem + BOFF + (wc * 64 + r15) * 128;
  f32x4 acc[MREP][4] = {};
  // ---- prologue (issue order matters for vmcnt: [A0, B0, A1])
  STG_A(0, 0);
  STG_B(0, 0);
  STG_A(1, 1);
  int sa = 0;
  for (int s = 0; s < NS; ++s) {
    __builtin_amdgcn_sched_barrier(0);
    asm volatile("s_waitcnt lgkmcnt(0)" ::: "memory");
    if (s < NS - 1) asm volatile("s_waitcnt vmcnt(4)" ::: "memory");
    else            asm volatile("s_waitcnt vmcnt(0)" ::: "memory");
    __builtin_amdgcn_s_barrier();
    __builtin_amdgcn_sched_barrier(0);
    if (s + 1 < NS) STG_B(s + 1, (s + 1) & 1);
    if (s + 2 < NS) { int s2 = sa + 2; if (s2 >= 3) s2 -= 3; STG_A(s + 2, s2); }
    const char* ab = arow + sa * ABUF;
    const char* bb = brow + (s & 1) * BBUF;
#pragma unroll
    for (int kk = 0; kk < 2; kk++) {
      const int ck = kk ? c1 : c0;
      bf16x8 af[MREP], bv[4];
#pragma unroll
      for (int mf = 0; mf < MREP; mf++)
        af[mf] = *(const bf16x8*)(ab + mf * 2048 + ck);
#pragma unroll
      for (int nf = 0; nf < 4; nf++)
        bv[nf] = *(const bf16x8*)(bb + nf * 2048 + ck);
#pragma unroll
      for (int mf = 0; mf < MREP; mf++)
#pragma unroll
        for (int nf = 0; nf < 4; nf++)
          acc[mf][nf] = __builtin_amdgcn_mfma_f32_16x16x32_bf16(
              af[mf], bv[nf], acc[mf][nf], 0, 0, 0);
    }
    sa++; if (sa == 3) sa = 0;
  }
#undef STG_A
#undef STG_B
  // ---- epilogue.  D layout: row=(l>>4)*4+reg, col=l&15 (m89/m91 verified).
  const int orow0 = bm * 256 + wr * WMT + q4 * 4;
  const int ocol0 = bn * BN_ + wc * 64 + r15;
  if (EPI == 0) {
    const int which = (bn * BN_) >> 10;  // uniform per block
#pragma unroll
    for (int mi = 0; mi < MREP; mi++)
#pragma unroll
      for (int ni = 0; ni < 4; ni++)
#pragma unroll
        for (int r = 0; r < 4; r++) {
          int m = orow0 + mi * 16 + r;
          int c = ocol0 + ni * 16;
          int cc = c & 1023;
          int h = cc >> 6, d = cc & 63;
          int b = m >> 10, n = m & 1023;
          float v = acc[mi][ni][r];
          if (which == 0)
            qout[(((size_t)(b * 16 + h)) * 1024 + n) * 64 + d] = f2bf(v * 0.125f);
          else if (which == 1)
            kout[(((size_t)(b * 16 + h)) * MKV + 64 + n) * 64 + d] = f2bf(v);
          else
            vout[(((size_t)(b * 16 + h)) * MKV + 64 + n) * 64 + d] = f2bf(v);
        }
  } else if (EPI == 1) {
#pragma unroll
    for (int mi = 0; mi < MREP; mi++)
#pragma unroll
      for (int ni = 0; ni < 4; ni++)
#pragma unroll
        for (int r = 0; r < 4; r++) {
          int c = ocol0 + ni * 16;
          size_t idx = (size_t)(orow0 + mi * 16 + r) * Ndim + c;
          outf[idx] = resid[idx] + acc[mi][ni][r] + bias[c];
        }
  } else {
#pragma unroll
    for (int mi = 0; mi < MREP; mi++)
#pragma unroll
      for (int ni = 0; ni < 4; ni++)
#pragma unroll
        for (int r = 0; r < 4; r++) {
          int c = ocol0 + ni * 16;
          size_t idx = (size_t)(orow0 + mi * 16 + r) * Ndim + c;
          float z = acc[mi][ni][r] + bias[c];
          outb[idx] = f2bf(z / (1.f + __expf(-1.702f * z)));
        }
  }
}

// ---------------------------------------------------------------------------
// Flash attention (round-3 version, verified): LDS-staged K/V double-buffered,
// swapped QK^T, 8 waves x 32 q-rows, grid (bh, qt).
__device__ __forceinline__ void online_sm(f32x4 S[4], float& m, float& lsum,
                                          f32x4 Oa[4], unsigned pw[4][2]) {
  float mx = S[0][0];
#pragma unroll
  for (int jc = 0; jc < 4; jc++)
#pragma unroll
    for (int r = 0; r < 4; r++) mx = fmaxf(mx, S[jc][r]);
  mx = fmaxf(mx, __shfl_xor(mx, 16));
  mx = fmaxf(mx, __shfl_xor(mx, 32));
  const float mn = fmaxf(m, mx);
  const float scl = __expf(m - mn);
  m = mn;
  float rs = 0.f;
#pragma unroll
  for (int jc = 0; jc < 4; jc++)
#pragma unroll
    for (int r = 0; r < 4; r++) {
      float p = __expf(S[jc][r] - mn);
      S[jc][r] = p;
      rs += p;
    }
  rs += __shfl_xor(rs, 16);
  rs += __shfl_xor(rs, 32);
  lsum = lsum * scl + rs;
#pragma unroll
  for (int db = 0; db < 4; db++)
#pragma unroll
    for (int r = 0; r < 4; r++) Oa[db][r] *= scl;
#pragma unroll
  for (int jc = 0; jc < 4; jc++) {
    pw[jc][0] = (unsigned)f2bf(S[jc][0]) | ((unsigned)f2bf(S[jc][1]) << 16);
    pw[jc][1] = (unsigned)f2bf(S[jc][2]) | ((unsigned)f2bf(S[jc][3]) << 16);
  }
}

__device__ __forceinline__ bf16x8 pexch(const unsigned pw[4][2], int kk,
                                        int src0, bool lo) {
  const unsigned a0 = pw[2 * kk][0], a1 = pw[2 * kk][1];
  const unsigned b0 = pw[2 * kk + 1][0], b1 = pw[2 * kk + 1][1];
  unsigned wA0 = (unsigned)__shfl((int)a0, src0);
  unsigned wA1 = (unsigned)__shfl((int)a1, src0);
  unsigned wB0 = (unsigned)__shfl((int)b0, src0);
  unsigned wB1 = (unsigned)__shfl((int)b1, src0);
  unsigned wA0h = (unsigned)__shfl((int)a0, src0 + 16);
  unsigned wA1h = (unsigned)__shfl((int)a1, src0 + 16);
  unsigned wB0h = (unsigned)__shfl((int)b0, src0 + 16);
  unsigned wB1h = (unsigned)__shfl((int)b1, src0 + 16);
  union { unsigned u[4]; bf16x8 v; } pf;
  pf.u[0] = lo ? wA0 : wB0;
  pf.u[1] = lo ? wA1 : wB1;
  pf.u[2] = lo ? wA0h : wB0h;
  pf.u[3] = lo ? wA1h : wB1h;
  return pf.v;
}

__global__ __launch_bounds__(512, 4) void flash_attn(
    const unsigned short* __restrict__ Qb, const unsigned short* __restrict__ Kb,
    const unsigned short* __restrict__ Vt, unsigned short* __restrict__ Ob) {
  __shared__ __align__(16) unsigned short KT[2][4096];
  __shared__ __align__(16) unsigned short VT[2][4096];
  const int t = threadIdx.x;
  const int w = t >> 6, l = t & 63;
  const int g = l >> 4, r15 = l & 15;
  const int bh = blockIdx.x, qt = blockIdx.y;
  const unsigned short* Kbh = Kb + (size_t)bh * MKV * 64;
  const unsigned short* Vbh = Vt + (size_t)bh * 64 * MKV;
  const int srow = t >> 3;
  const int scb = ((t & 7) << 4) ^ ((srow & 7) << 4);
  const char* Ksrc0 = (const char*)Kbh + srow * 128 + scb;
  const char* Vsrc0 = (const char*)Vbh + srow * (MKV * 2) + scb;
  const int qbase = qt * 256 + w * 32;
  const unsigned short* Qr0 = Qb + ((size_t)bh * 1024 + qbase + r15) * 64;
  const bf16x8 qf00 = *(const bf16x8*)(Qr0 + g * 8);
  const bf16x8 qf01 = *(const bf16x8*)(Qr0 + 32 + g * 8);
  const bf16x8 qf10 = *(const bf16x8*)(Qr0 + 16 * 64 + g * 8);
  const bf16x8 qf11 = *(const bf16x8*)(Qr0 + 16 * 64 + 32 + g * 8);
  f32x4 Oa0[4] = {}, Oa1[4] = {};
  float m0 = -1e30f, l0 = 0.f, m1 = -1e30f, l1 = 0.f;
  const int src0 = r15 + ((l & 16) << 1);
  const bool lo = (l < 32);
  const int rx = (r15 & 7) << 4;
  GLDS16(Ksrc0, &KT[0][t * 8]);
  GLDS16(Vsrc0, &VT[0][t * 8]);
  __syncthreads();
  int cur = 0;
  for (int kt = 0; kt < 17; ++kt) {
    if (kt < 16) {
      GLDS16(Ksrc0 + (kt + 1) * 8192, &KT[cur ^ 1][t * 8]);
      GLDS16(Vsrc0 + (kt + 1) * 128, &VT[cur ^ 1][t * 8]);
    }
    const char* Kl = (const char*)&KT[cur][0];
    const char* Vl = (const char*)&VT[cur][0];
    f32x4 S0[4], S1[4];
#pragma unroll
    for (int jc = 0; jc < 4; jc++) {
      const char* kr = Kl + jc * 2048 + r15 * 128;
      bf16x8 k0 = *(const bf16x8*)(kr + ((g * 16) ^ rx));
      bf16x8 k1 = *(const bf16x8*)(kr + ((64 + g * 16) ^ rx));
      f32x4 a0 = {}, a1 = {};
      a0 = __builtin_amdgcn_mfma_f32_16x16x32_bf16(k0, qf00, a0, 0, 0, 0);
      a0 = __builtin_amdgcn_mfma_f32_16x16x32_bf16(k1, qf01, a0, 0, 0, 0);
      a1 = __builtin_amdgcn_mfma_f32_16x16x32_bf16(k0, qf10, a1, 0, 0, 0);
      a1 = __builtin_amdgcn_mfma_f32_16x16x32_bf16(k1, qf11, a1, 0, 0, 0);
      S0[jc] = a0; S1[jc] = a1;
    }
    unsigned pw0[4][2], pw1[4][2];
    online_sm(S0, m0, l0, Oa0, pw0);
    online_sm(S1, m1, l1, Oa1, pw1);
#pragma unroll
    for (int kk = 0; kk < 2; kk++) {
      bf16x8 pf0 = pexch(pw0, kk, src0, lo);
      bf16x8 pf1 = pexch(pw1, kk, src0, lo);
#pragma unroll
      for (int db = 0; db < 4; db++) {
        bf16x8 va = *(const bf16x8*)(Vl + db * 2048 + r15 * 128 +
                                     ((kk * 64 + g * 16) ^ rx));
        Oa0[db] = __builtin_amdgcn_mfma_f32_16x16x32_bf16(va, pf0, Oa0[db], 0, 0, 0);
        Oa1[db] = __builtin_amdgcn_mfma_f32_16x16x32_bf16(va, pf1, Oa1[db], 0, 0, 0);
      }
    }
    __syncthreads();
    cur ^= 1;
  }
  const int b = bh >> 4, h = bh & 15;
  const float i0 = 1.f / l0, i1 = 1.f / l1;
  const int n0 = qbase + r15;
#pragma unroll
  for (int db = 0; db < 4; db++) {
    u16x4 o;
#pragma unroll
    for (int r = 0; r < 4; r++) o[r] = f2bf(Oa0[db][r] * i0);
    *(u16x4*)(Ob + ((size_t)b * 1024 + n0) * 1024 + h * 64 + db * 16 + g * 4) = o;
#pragma unroll
    for (int r = 0; r < 4; r++) o[r] = f2bf(Oa1[db][r] * i1);
    *(u16x4*)(Ob + ((size_t)b * 1024 + n0 + 16) * 1024 + h * 64 + db * 16 + g * 4) = o;
  }
}

// ---------------------------------------------------------------------------
extern "C" void kernel_launch(void* const* d_in, const int* in_sizes, int n_in,
                              void* d_out, int out_size, void* d_ws, size_t ws_size,
                              hipStream_t stream) {
  const float* x       = (const float*)d_in[0];
  const float* pk      = (const float*)d_in[1];
  const float* pv      = (const float*)d_in[2];
  const float* qkv_w   = (const float*)d_in[3];
  const float* proj_w  = (const float*)d_in[4];
  const float* proj_b  = (const float*)d_in[5];
  const float* ln1_g   = (const float*)d_in[6];
  const float* ln1_b   = (const float*)d_in[7];
  const float* ln2_g   = (const float*)d_in[8];
  const float* ln2_b   = (const float*)d_in[9];
  const float* fc_w    = (const float*)d_in[10];
  const float* fc_b    = (const float*)d_in[11];
  const float* cproj_w = (const float*)d_in[12];
  const float* cproj_b = (const float*)d_in[13];
  float* out = (float*)d_out;
  char* ws = (char*)d_ws;

  unsigned short* qkv_wb   = (unsigned short*)(ws + 0);          // 6291456
  unsigned short* proj_wb  = (unsigned short*)(ws + 6291456);    // 2097152
  unsigned short* fc_wb    = (unsigned short*)(ws + 8388608);    // 8388608
  unsigned short* cproj_wb = (unsigned short*)(ws + 16777216);   // 8388608
  float*          x1       = (float*)(ws + 25165824);            // 33554432
  unsigned short* h1       = (unsigned short*)(ws + 58720256);   // 16777216
  unsigned short* o_b      = h1;                                 // alias (h1 dead)
  unsigned short* h2       = (unsigned short*)(ws + 75497472);   // 16777216
  unsigned short* q_buf    = (unsigned short*)(ws + 92274688);   // 16777216
  unsigned short* Kb       = (unsigned short*)(ws + 109051904);  // 17825792
  unsigned short* Vb       = (unsigned short*)(ws + 126877696);  // 17825792
  unsigned short* Vt       = (unsigned short*)(ws + 144703488);  // 17825792
  unsigned short* h3       = (unsigned short*)(ws + 92274688);   // alias (dead)
  if (ws_size < 162529280u) return;

  // allow big dynamic LDS (idempotent host-side calls — capture-safe)
  (void)hipFuncSetAttribute((const void*)gemmw<0, 256>,
      hipFuncAttributeMaxDynamicSharedMemorySize, 163840);
  (void)hipFuncSetAttribute((const void*)gemmw<2, 256>,
      hipFuncAttributeMaxDynamicSharedMemorySize, 163840);
  (void)hipFuncSetAttribute((const void*)gemmw<1, 128>,
      hipFuncAttributeMaxDynamicSharedMemorySize, 131072);

  cast_bf16_k<<<1536, 256, 0, stream>>>(qkv_w, qkv_wb, 393216);
  cast_bf16_k<<<512, 256, 0, stream>>>(proj_w, proj_wb, 131072);
  cast_bf16_k<<<2048, 256, 0, stream>>>(fc_w, fc_wb, 524288);
  cast_bf16_k<<<2048, 256, 0, stream>>>(cproj_w, cproj_wb, 524288);
  ln_bf16<<<ROWS, 256, 0, stream>>>(x, ln1_g, ln1_b, h1);
  prefix_fill<<<256, 256, 0, stream>>>(pk, pv, Kb, Vb);
  gemmw<0, 256><<<dim3(32, 12), 512, 163840, stream>>>(
      h1, qkv_wb, nullptr, nullptr, nullptr, nullptr, q_buf, Kb, Vb, 3072, 1024);
  transpose_v<<<dim3(17, 128), 256, 0, stream>>>(Vb, Vt);
  flash_attn<<<dim3(128, 4), 512, 0, stream>>>(q_buf, Kb, Vt, o_b);
  gemmw<1, 128><<<dim3(32, 8), 512, 131072, stream>>>(
      o_b, proj_wb, proj_b, x, x1, nullptr, nullptr, nullptr, nullptr, 1024, 1024);
  ln_bf16<<<ROWS, 256, 0, stream>>>(x1, ln2_g, ln2_b, h2);
  gemmw<2, 256><<<dim3(32, 16), 512, 163840, stream>>>(
      h2, fc_wb, fc_b, nullptr, nullptr, h3, nullptr, nullptr, nullptr, 4096, 1024);
  gemmw<1, 128><<<dim3(32, 8), 512, 131072, stream>>>(
      h3, cproj_wb, cproj_b, x1, out, nullptr, nullptr, nullptr, nullptr, 1024, 4096);
}

// Round 7
// 363.074 us; speedup vs baseline: 1.0700x; 1.0700x over previous
//
#include <hip/hip_runtime.h>

// Problem constants
#define B_   8
#define N_   1024
#define C_   1024
#define H_   16
#define P_   64
#define D_   64
#define MKV  1088      // P_ + N_
#define ROWS 8192      // B_*N_

typedef float f32x4 __attribute__((ext_vector_type(4)));
typedef __bf16 bf16x8 __attribute__((ext_vector_type(8)));
typedef unsigned short u16x8 __attribute__((ext_vector_type(8)));
typedef unsigned short u16x4 __attribute__((ext_vector_type(4)));

__device__ __forceinline__ unsigned short f2bf(float f) {
  unsigned u = __float_as_uint(f);
  u += 0x7fffu + ((u >> 16) & 1u);   // round-to-nearest-even
  return (unsigned short)(u >> 16);
}

#define GLDS16(g, l)                                                          \
  __builtin_amdgcn_global_load_lds(                                           \
      (const __attribute__((address_space(1))) void*)(g),                     \
      (__attribute__((address_space(3))) void*)(l), 16, 0, 0)

// ---------------------------------------------------------------------------
__global__ __launch_bounds__(256) void cast_bf16_k(
    const float* __restrict__ in, unsigned short* __restrict__ out, int n8) {
  int i = blockIdx.x * 256 + threadIdx.x;
  if (i >= n8) return;
  const float4 a = ((const float4*)in)[i * 2];
  const float4 c = ((const float4*)in)[i * 2 + 1];
  u16x8 o;
  o[0] = f2bf(a.x); o[1] = f2bf(a.y); o[2] = f2bf(a.z); o[3] = f2bf(a.w);
  o[4] = f2bf(c.x); o[5] = f2bf(c.y); o[6] = f2bf(c.z); o[7] = f2bf(c.w);
  *(u16x8*)(out + (size_t)i * 8) = o;
}

// ---------------------------------------------------------------------------
__global__ __launch_bounds__(256) void ln_bf16(
    const float* __restrict__ x, const float* __restrict__ g,
    const float* __restrict__ b, unsigned short* __restrict__ out) {
  const int row = blockIdx.x, t = threadIdx.x;
  const float4 v = ((const float4*)(x + (size_t)row * 1024))[t];
  float s  = v.x + v.y + v.z + v.w;
  float s2 = v.x * v.x + v.y * v.y + v.z * v.z + v.w * v.w;
#pragma unroll
  for (int m = 1; m < 64; m <<= 1) {
    s  += __shfl_xor(s, m);
    s2 += __shfl_xor(s2, m);
  }
  __shared__ float red[8];
  if ((t & 63) == 0) { red[t >> 6] = s; red[4 + (t >> 6)] = s2; }
  __syncthreads();
  s  = red[0] + red[1] + red[2] + red[3];
  s2 = red[4] + red[5] + red[6] + red[7];
  const float mu = s * (1.0f / 1024.0f);
  const float rs = rsqrtf(s2 * (1.0f / 1024.0f) - mu * mu + 1e-5f);
  const float4 gv = ((const float4*)g)[t];
  const float4 bv = ((const float4*)b)[t];
  u16x4 o;
  o[0] = f2bf((v.x - mu) * rs * gv.x + bv.x);
  o[1] = f2bf((v.y - mu) * rs * gv.y + bv.y);
  o[2] = f2bf((v.z - mu) * rs * gv.z + bv.z);
  o[3] = f2bf((v.w - mu) * rs * gv.w + bv.w);
  *(u16x4*)(out + (size_t)row * 1024 + t * 4) = o;
}

// ---------------------------------------------------------------------------
__global__ __launch_bounds__(256) void prefix_fill(
    const float* __restrict__ pk, const float* __restrict__ pv,
    unsigned short* __restrict__ Kb, unsigned short* __restrict__ Vb) {
  int i = blockIdx.x * 256 + threadIdx.x;
  int c8 = i & 127, bp = i >> 7;
  int b = bp >> 6, p = bp & 63;
  int c = c8 << 3, h = c >> 6, d = c & 63;
  size_t sidx = (size_t)bp * 1024 + c;
  size_t didx = (((size_t)(b * 16 + h)) * MKV + p) * 64 + d;
  float4 a = *(const float4*)(pk + sidx);
  float4 a2 = *(const float4*)(pk + sidx + 4);
  u16x8 o;
  o[0] = f2bf(a.x);  o[1] = f2bf(a.y);  o[2] = f2bf(a.z);  o[3] = f2bf(a.w);
  o[4] = f2bf(a2.x); o[5] = f2bf(a2.y); o[6] = f2bf(a2.z); o[7] = f2bf(a2.w);
  *(u16x8*)(Kb + didx) = o;
  a = *(const float4*)(pv + sidx);
  a2 = *(const float4*)(pv + sidx + 4);
  o[0] = f2bf(a.x);  o[1] = f2bf(a.y);  o[2] = f2bf(a.z);  o[3] = f2bf(a.w);
  o[4] = f2bf(a2.x); o[5] = f2bf(a2.y); o[6] = f2bf(a2.z); o[7] = f2bf(a2.w);
  *(u16x8*)(Vb + didx) = o;
}

// ---------------------------------------------------------------------------
__global__ __launch_bounds__(256) void transpose_v(
    const unsigned short* __restrict__ Vb, unsigned short* __restrict__ Vt) {
  __shared__ __align__(16) unsigned short Ts[64 * 66];
  const int kt = blockIdx.x, bh = blockIdx.y;
  const int t = threadIdx.x;
  const unsigned short* src = Vb + ((size_t)bh * MKV + kt * 64) * 64;
#pragma unroll
  for (int rnd = 0; rnd < 2; rnd++) {
    int chunk = rnd * 256 + t;
    int mr = chunk >> 3, d0 = (chunk & 7) << 3;
    u16x8 a = *(const u16x8*)(src + mr * 64 + d0);
#pragma unroll
    for (int j = 0; j < 8; j += 2)
      *(unsigned*)&Ts[mr * 66 + d0 + j] = (unsigned)a[j] | ((unsigned)a[j + 1] << 16);
  }
  __syncthreads();
#pragma unroll
  for (int rnd = 0; rnd < 2; rnd++) {
    int chunk = rnd * 256 + t;
    int dr = chunk >> 3, m0 = (chunk & 7) << 3;
    u16x8 o;
#pragma unroll
    for (int j = 0; j < 8; j++) o[j] = Ts[(m0 + j) * 66 + dr];
    *(u16x8*)(Vt + ((size_t)bh * 64 + dr) * MKV + kt * 64 + m0) = o;
  }
}

// ---------------------------------------------------------------------------
// GEMM "gemmp": C[M,Nd] = A[M,K] @ Bw[Nd,K]^T, bf16 in, fp32 accum.
// R6-verified staging/liveness/vmcnt (A ring of 3, B ring of 2, boundary
// vmcnt(4), one lgkm-drained barrier per tile) + m201-style PHASE-SPLIT
// compute: BN=256 -> 4 phases/tile {stage || ds_read subtile || setprio 16
// MFMA || barrier}, B-frags reg-cached across ms phases; BN=128 -> 2 phases.
// XCD slab swizzle: each XCD owns a 4-bm slab (A L2-resident).
template <int EPI, int BN_>
__global__ __launch_bounds__(512, 2) void gemmp(
    const unsigned short* __restrict__ A, const unsigned short* __restrict__ Bw,
    const float* __restrict__ bias, const float* __restrict__ resid,
    float* __restrict__ outf, unsigned short* __restrict__ outb,
    unsigned short* __restrict__ qout, unsigned short* __restrict__ kout,
    unsigned short* __restrict__ vout, int Ndim, int Kdim) {
  constexpr int WN   = BN_ / 64;              // waves along N: 4 or 2
  constexpr int WMT  = (WN == 4) ? 128 : 64;  // per-wave M
  constexpr int MREP = WMT / 16;              // 8 or 4
  constexpr int ABUF = 32768;                 // 256 rows x 128B
  constexpr int BBUF = BN_ * 128;
  constexpr int BOFF = 3 * ABUF;              // 98304
  extern __shared__ __align__(16) char smem[];
  const int t = threadIdx.x;
  const int w = t >> 6, l = t & 63;
  const int wr = w / WN, wc = w % WN;
  const int q4 = l >> 4, r15 = l & 15;
  // XCD slab swizzle: gridDim.x == 32 always; xcd = fid%8 owns bm slab of 4.
  const int fid = (int)blockIdx.y * 32 + blockIdx.x;
  const int j8 = fid >> 3;
  const int bm = ((fid & 7) << 2) + (j8 & 3);
  const int bn = j8 >> 2;
  const int NS = Kdim >> 6;
  // ---- staging (pre-swizzled source, linear LDS dest = base + t*16)
  const int sr = t >> 3, scolb = (t & 7) << 4;
  const int sswz = scolb ^ ((sr & 7) << 4);
  const size_t rb = (size_t)Kdim * 2;
  const char* As0 = (const char*)A + (size_t)(bm * 256 + sr) * rb + sswz;
  const char* Bs0 = (const char*)Bw + (size_t)(bn * BN_ + sr) * rb + sswz;
  char* Adst = smem + t * 16;
  char* Bdst = smem + BOFF + t * 16;
#define STG_AH(s_, st_, h_) {                                                 \
    const int ko = (s_) << 7;                                                 \
    GLDS16(As0 + ((h_) * 128) * rb + ko,                                      \
           Adst + (st_) * ABUF + (h_) * 16384);                               \
    GLDS16(As0 + ((h_) * 128 + 64) * rb + ko,                                 \
           Adst + (st_) * ABUF + (h_) * 16384 + 8192); }
#define STG_B(s_, sb_) {                                                      \
    const int ko = (s_) << 7;                                                 \
    GLDS16(Bs0 + ko,           Bdst + (sb_) * BBUF);                          \
    GLDS16(Bs0 + 64 * rb + ko, Bdst + (sb_) * BBUF + 8192);                   \
    if (BN_ == 256) {                                                         \
      GLDS16(Bs0 + 128 * rb + ko, Bdst + (sb_) * BBUF + 16384);               \
      GLDS16(Bs0 + 192 * rb + ko, Bdst + (sb_) * BBUF + 24576); } }
  // ---- fragment read bases (swizzled ds_read)
  const int rx = (r15 & 7) << 4;
  const int c0 = (q4 << 4) ^ rx;
  const int c1 = c0 ^ 64;
  const char* arow = smem + (wr * WMT + r15) * 128;
  const char* brow = smem + BOFF + (wc * 64 + r15) * 128;
  f32x4 acc[MREP][4] = {};
#define RD_A(ms_, ck_)                                                        \
  _Pragma("unroll") for (int mf = 0; mf < 4; mf++)                            \
    af[mf] = *(const bf16x8*)(ab + ((ms_) * 64 + mf * 16) * 128 + (ck_));
#define RD_B(ck_)                                                             \
  _Pragma("unroll") for (int nf = 0; nf < 4; nf++)                            \
    bv[nf] = *(const bf16x8*)(bb + nf * 2048 + (ck_));
#define MFMA16(ms_)                                                           \
  __builtin_amdgcn_s_setprio(1);                                              \
  _Pragma("unroll") for (int mf = 0; mf < 4; mf++)                            \
  _Pragma("unroll") for (int nf = 0; nf < 4; nf++)                            \
    acc[(ms_) * 4 + mf][nf] = __builtin_amdgcn_mfma_f32_16x16x32_bf16(        \
        af[mf], bv[nf], acc[(ms_) * 4 + mf][nf], 0, 0, 0);                    \
  __builtin_amdgcn_s_setprio(0);
#define PB()                                                                  \
  __builtin_amdgcn_sched_barrier(0);                                          \
  __builtin_amdgcn_s_barrier();                                               \
  __builtin_amdgcn_sched_barrier(0);
  // ---- prologue (issue order: A0, B0, A1 — same as R6-verified)
  STG_AH(0, 0, 0); STG_AH(0, 0, 1);
  STG_B(0, 0);
  STG_AH(1, 1, 0); STG_AH(1, 1, 1);
  int sa = 0;
  for (int s = 0; s < NS; ++s) {
    __builtin_amdgcn_sched_barrier(0);
    asm volatile("s_waitcnt lgkmcnt(0)" ::: "memory");
    if (s < NS - 1) asm volatile("s_waitcnt vmcnt(4)" ::: "memory");
    else            asm volatile("s_waitcnt vmcnt(0)" ::: "memory");
    __builtin_amdgcn_s_barrier();
    __builtin_amdgcn_sched_barrier(0);
    int sa2 = sa + 2; if (sa2 >= 3) sa2 -= 3;
    const char* ab = arow + sa * ABUF;
    const char* bb = brow + (s & 1) * BBUF;
    bf16x8 af[4], bv[4];
    if constexpr (WN == 4) {
      // P1: stage B(s+1) | read A(ms0,k0)+B(k0) | MFMA(ms0,k0)
      if (s + 1 < NS) STG_B(s + 1, (s + 1) & 1);
      RD_A(0, c0); RD_B(c0);
      MFMA16(0);
      PB();
      // P2: stage A(s+2) half0 | read A(ms1,k0) | MFMA(ms1,k0)  (bv reused)
      if (s + 2 < NS) STG_AH(s + 2, sa2, 0);
      RD_A(1, c0);
      MFMA16(1);
      PB();
      // P3: stage A(s+2) half1 | read A(ms0,k1)+B(k1) | MFMA(ms0,k1)
      if (s + 2 < NS) STG_AH(s + 2, sa2, 1);
      RD_A(0, c1); RD_B(c1);
      MFMA16(0);
      PB();
      // P4: read A(ms1,k1) | MFMA(ms1,k1)   (entry barrier of s+1 closes)
      RD_A(1, c1);
      MFMA16(1);
    } else {
      // P1: stage B(s+1) | read A(k0)+B(k0) | 16 MFMA
      if (s + 1 < NS) STG_B(s + 1, (s + 1) & 1);
      RD_A(0, c0); RD_B(c0);
      MFMA16(0);
      PB();
      // P2: stage A(s+2) | read A(k1)+B(k1) | 16 MFMA
      if (s + 2 < NS) { STG_AH(s + 2, sa2, 0); STG_AH(s + 2, sa2, 1); }
      RD_A(0, c1); RD_B(c1);
      MFMA16(0);
    }
    sa++; if (sa == 3) sa = 0;
  }
#undef STG_AH
#undef STG_B
#undef RD_A
#undef RD_B
#undef MFMA16
#undef PB
  // ---- epilogue.  D layout: row=(l>>4)*4+reg, col=l&15 (m89/m91 verified).
  const int orow0 = bm * 256 + wr * WMT + q4 * 4;
  const int ocol0 = bn * BN_ + wc * 64 + r15;
  if (EPI == 0) {
    const int which = (bn * BN_) >> 10;  // uniform per block
#pragma unroll
    for (int mi = 0; mi < MREP; mi++)
#pragma unroll
      for (int ni = 0; ni < 4; ni++)
#pragma unroll
        for (int r = 0; r < 4; r++) {
          int m = orow0 + mi * 16 + r;
          int c = ocol0 + ni * 16;
          int cc = c & 1023;
          int h = cc >> 6, d = cc & 63;
          int b = m >> 10, n = m & 1023;
          float v = acc[mi][ni][r];
          if (which == 0)
            qout[(((size_t)(b * 16 + h)) * 1024 + n) * 64 + d] = f2bf(v * 0.125f);
          else if (which == 1)
            kout[(((size_t)(b * 16 + h)) * MKV + 64 + n) * 64 + d] = f2bf(v);
          else
            vout[(((size_t)(b * 16 + h)) * MKV + 64 + n) * 64 + d] = f2bf(v);
        }
  } else if (EPI == 1) {
#pragma unroll
    for (int mi = 0; mi < MREP; mi++)
#pragma unroll
      for (int ni = 0; ni < 4; ni++)
#pragma unroll
        for (int r = 0; r < 4; r++) {
          int c = ocol0 + ni * 16;
          size_t idx = (size_t)(orow0 + mi * 16 + r) * Ndim + c;
          outf[idx] = resid[idx] + acc[mi][ni][r] + bias[c];
        }
  } else {
#pragma unroll
    for (int mi = 0; mi < MREP; mi++)
#pragma unroll
      for (int ni = 0; ni < 4; ni++)
#pragma unroll
        for (int r = 0; r < 4; r++) {
          int c = ocol0 + ni * 16;
          size_t idx = (size_t)(orow0 + mi * 16 + r) * Ndim + c;
          float z = acc[mi][ni][r] + bias[c];
          outb[idx] = f2bf(z / (1.f + __expf(-1.702f * z)));
        }
  }
}

// ---------------------------------------------------------------------------
// Flash attention (round-3 version, verified): LDS-staged K/V double-buffered,
// swapped QK^T, 8 waves x 32 q-rows, grid (bh, qt).
__device__ __forceinline__ void online_sm(f32x4 S[4], float& m, float& lsum,
                                          f32x4 Oa[4], unsigned pw[4][2]) {
  float mx = S[0][0];
#pragma unroll
  for (int jc = 0; jc < 4; jc++)
#pragma unroll
    for (int r = 0; r < 4; r++) mx = fmaxf(mx, S[jc][r]);
  mx = fmaxf(mx, __shfl_xor(mx, 16));
  mx = fmaxf(mx, __shfl_xor(mx, 32));
  const float mn = fmaxf(m, mx);
  const float scl = __expf(m - mn);
  m = mn;
  float rs = 0.f;
#pragma unroll
  for (int jc = 0; jc < 4; jc++)
#pragma unroll
    for (int r = 0; r < 4; r++) {
      float p = __expf(S[jc][r] - mn);
      S[jc][r] = p;
      rs += p;
    }
  rs += __shfl_xor(rs, 16);
  rs += __shfl_xor(rs, 32);
  lsum = lsum * scl + rs;
#pragma unroll
  for (int db = 0; db < 4; db++)
#pragma unroll
    for (int r = 0; r < 4; r++) Oa[db][r] *= scl;
#pragma unroll
  for (int jc = 0; jc < 4; jc++) {
    pw[jc][0] = (unsigned)f2bf(S[jc][0]) | ((unsigned)f2bf(S[jc][1]) << 16);
    pw[jc][1] = (unsigned)f2bf(S[jc][2]) | ((unsigned)f2bf(S[jc][3]) << 16);
  }
}

__device__ __forceinline__ bf16x8 pexch(const unsigned pw[4][2], int kk,
                                        int src0, bool lo) {
  const unsigned a0 = pw[2 * kk][0], a1 = pw[2 * kk][1];
  const unsigned b0 = pw[2 * kk + 1][0], b1 = pw[2 * kk + 1][1];
  unsigned wA0 = (unsigned)__shfl((int)a0, src0);
  unsigned wA1 = (unsigned)__shfl((int)a1, src0);
  unsigned wB0 = (unsigned)__shfl((int)b0, src0);
  unsigned wB1 = (unsigned)__shfl((int)b1, src0);
  unsigned wA0h = (unsigned)__shfl((int)a0, src0 + 16);
  unsigned wA1h = (unsigned)__shfl((int)a1, src0 + 16);
  unsigned wB0h = (unsigned)__shfl((int)b0, src0 + 16);
  unsigned wB1h = (unsigned)__shfl((int)b1, src0 + 16);
  union { unsigned u[4]; bf16x8 v; } pf;
  pf.u[0] = lo ? wA0 : wB0;
  pf.u[1] = lo ? wA1 : wB1;
  pf.u[2] = lo ? wA0h : wB0h;
  pf.u[3] = lo ? wA1h : wB1h;
  return pf.v;
}

__global__ __launch_bounds__(512, 4) void flash_attn(
    const unsigned short* __restrict__ Qb, const unsigned short* __restrict__ Kb,
    const unsigned short* __restrict__ Vt, unsigned short* __restrict__ Ob) {
  __shared__ __align__(16) unsigned short KT[2][4096];
  __shared__ __align__(16) unsigned short VT[2][4096];
  const int t = threadIdx.x;
  const int w = t >> 6, l = t & 63;
  const int g = l >> 4, r15 = l & 15;
  const int bh = blockIdx.x, qt = blockIdx.y;
  const unsigned short* Kbh = Kb + (size_t)bh * MKV * 64;
  const unsigned short* Vbh = Vt + (size_t)bh * 64 * MKV;
  const int srow = t >> 3;
  const int scb = ((t & 7) << 4) ^ ((srow & 7) << 4);
  const char* Ksrc0 = (const char*)Kbh + srow * 128 + scb;
  const char* Vsrc0 = (const char*)Vbh + srow * (MKV * 2) + scb;
  const int qbase = qt * 256 + w * 32;
  const unsigned short* Qr0 = Qb + ((size_t)bh * 1024 + qbase + r15) * 64;
  const bf16x8 qf00 = *(const bf16x8*)(Qr0 + g * 8);
  const bf16x8 qf01 = *(const bf16x8*)(Qr0 + 32 + g * 8);
  const bf16x8 qf10 = *(const bf16x8*)(Qr0 + 16 * 64 + g * 8);
  const bf16x8 qf11 = *(const bf16x8*)(Qr0 + 16 * 64 + 32 + g * 8);
  f32x4 Oa0[4] = {}, Oa1[4] = {};
  float m0 = -1e30f, l0 = 0.f, m1 = -1e30f, l1 = 0.f;
  const int src0 = r15 + ((l & 16) << 1);
  const bool lo = (l < 32);
  const int rx = (r15 & 7) << 4;
  GLDS16(Ksrc0, &KT[0][t * 8]);
  GLDS16(Vsrc0, &VT[0][t * 8]);
  __syncthreads();
  int cur = 0;
  for (int kt = 0; kt < 17; ++kt) {
    if (kt < 16) {
      GLDS16(Ksrc0 + (kt + 1) * 8192, &KT[cur ^ 1][t * 8]);
      GLDS16(Vsrc0 + (kt + 1) * 128, &VT[cur ^ 1][t * 8]);
    }
    const char* Kl = (const char*)&KT[cur][0];
    const char* Vl = (const char*)&VT[cur][0];
    f32x4 S0[4], S1[4];
#pragma unroll
    for (int jc = 0; jc < 4; jc++) {
      const char* kr = Kl + jc * 2048 + r15 * 128;
      bf16x8 k0 = *(const bf16x8*)(kr + ((g * 16) ^ rx));
      bf16x8 k1 = *(const bf16x8*)(kr + ((64 + g * 16) ^ rx));
      f32x4 a0 = {}, a1 = {};
      a0 = __builtin_amdgcn_mfma_f32_16x16x32_bf16(k0, qf00, a0, 0, 0, 0);
      a0 = __builtin_amdgcn_mfma_f32_16x16x32_bf16(k1, qf01, a0, 0, 0, 0);
      a1 = __builtin_amdgcn_mfma_f32_16x16x32_bf16(k0, qf10, a1, 0, 0, 0);
      a1 = __builtin_amdgcn_mfma_f32_16x16x32_bf16(k1, qf11, a1, 0, 0, 0);
      S0[jc] = a0; S1[jc] = a1;
    }
    unsigned pw0[4][2], pw1[4][2];
    online_sm(S0, m0, l0, Oa0, pw0);
    online_sm(S1, m1, l1, Oa1, pw1);
#pragma unroll
    for (int kk = 0; kk < 2; kk++) {
      bf16x8 pf0 = pexch(pw0, kk, src0, lo);
      bf16x8 pf1 = pexch(pw1, kk, src0, lo);
#pragma unroll
      for (int db = 0; db < 4; db++) {
        bf16x8 va = *(const bf16x8*)(Vl + db * 2048 + r15 * 128 +
                                     ((kk * 64 + g * 16) ^ rx));
        Oa0[db] = __builtin_amdgcn_mfma_f32_16x16x32_bf16(va, pf0, Oa0[db], 0, 0, 0);
        Oa1[db] = __builtin_amdgcn_mfma_f32_16x16x32_bf16(va, pf1, Oa1[db], 0, 0, 0);
      }
    }
    __syncthreads();
    cur ^= 1;
  }
  const int b = bh >> 4, h = bh & 15;
  const float i0 = 1.f / l0, i1 = 1.f / l1;
  const int n0 = qbase + r15;
#pragma unroll
  for (int db = 0; db < 4; db++) {
    u16x4 o;
#pragma unroll
    for (int r = 0; r < 4; r++) o[r] = f2bf(Oa0[db][r] * i0);
    *(u16x4*)(Ob + ((size_t)b * 1024 + n0) * 1024 + h * 64 + db * 16 + g * 4) = o;
#pragma unroll
    for (int r = 0; r < 4; r++) o[r] = f2bf(Oa1[db][r] * i1);
    *(u16x4*)(Ob + ((size_t)b * 1024 + n0 + 16) * 1024 + h * 64 + db * 16 + g * 4) = o;
  }
}

// ---------------------------------------------------------------------------
extern "C" void kernel_launch(void* const* d_in, const int* in_sizes, int n_in,
                              void* d_out, int out_size, void* d_ws, size_t ws_size,
                              hipStream_t stream) {
  const float* x       = (const float*)d_in[0];
  const float* pk      = (const float*)d_in[1];
  const float* pv      = (const float*)d_in[2];
  const float* qkv_w   = (const float*)d_in[3];
  const float* proj_w  = (const float*)d_in[4];
  const float* proj_b  = (const float*)d_in[5];
  const float* ln1_g   = (const float*)d_in[6];
  const float* ln1_b   = (const float*)d_in[7];
  const float* ln2_g   = (const float*)d_in[8];
  const float* ln2_b   = (const float*)d_in[9];
  const float* fc_w    = (const float*)d_in[10];
  const float* fc_b    = (const float*)d_in[11];
  const float* cproj_w = (const float*)d_in[12];
  const float* cproj_b = (const float*)d_in[13];
  float* out = (float*)d_out;
  char* ws = (char*)d_ws;

  unsigned short* qkv_wb   = (unsigned short*)(ws + 0);          // 6291456
  unsigned short* proj_wb  = (unsigned short*)(ws + 6291456);    // 2097152
  unsigned short* fc_wb    = (unsigned short*)(ws + 8388608);    // 8388608
  unsigned short* cproj_wb = (unsigned short*)(ws + 16777216);   // 8388608
  float*          x1       = (float*)(ws + 25165824);            // 33554432
  unsigned short* h1       = (unsigned short*)(ws + 58720256);   // 16777216
  unsigned short* o_b      = h1;                                 // alias (h1 dead)
  unsigned short* h2       = (unsigned short*)(ws + 75497472);   // 16777216
  unsigned short* q_buf    = (unsigned short*)(ws + 92274688);   // 16777216
  unsigned short* Kb       = (unsigned short*)(ws + 109051904);  // 17825792
  unsigned short* Vb       = (unsigned short*)(ws + 126877696);  // 17825792
  unsigned short* Vt       = (unsigned short*)(ws + 144703488);  // 17825792
  unsigned short* h3       = (unsigned short*)(ws + 92274688);   // alias (dead)
  if (ws_size < 162529280u) return;

  // allow big dynamic LDS (idempotent host-side calls — capture-safe)
  (void)hipFuncSetAttribute((const void*)gemmp<0, 256>,
      hipFuncAttributeMaxDynamicSharedMemorySize, 163840);
  (void)hipFuncSetAttribute((const void*)gemmp<2, 256>,
      hipFuncAttributeMaxDynamicSharedMemorySize, 163840);
  (void)hipFuncSetAttribute((const void*)gemmp<1, 128>,
      hipFuncAttributeMaxDynamicSharedMemorySize, 131072);

  cast_bf16_k<<<1536, 256, 0, stream>>>(qkv_w, qkv_wb, 393216);
  cast_bf16_k<<<512, 256, 0, stream>>>(proj_w, proj_wb, 131072);
  cast_bf16_k<<<2048, 256, 0, stream>>>(fc_w, fc_wb, 524288);
  cast_bf16_k<<<2048, 256, 0, stream>>>(cproj_w, cproj_wb, 524288);
  ln_bf16<<<ROWS, 256, 0, stream>>>(x, ln1_g, ln1_b, h1);
  prefix_fill<<<256, 256, 0, stream>>>(pk, pv, Kb, Vb);
  gemmp<0, 256><<<dim3(32, 12), 512, 163840, stream>>>(
      h1, qkv_wb, nullptr, nullptr, nullptr, nullptr, q_buf, Kb, Vb, 3072, 1024);
  transpose_v<<<dim3(17, 128), 256, 0, stream>>>(Vb, Vt);
  flash_attn<<<dim3(128, 4), 512, 0, stream>>>(q_buf, Kb, Vt, o_b);
  gemmp<1, 128><<<dim3(32, 8), 512, 131072, stream>>>(
      o_b, proj_wb, proj_b, x, x1, nullptr, nullptr, nullptr, nullptr, 1024, 1024);
  ln_bf16<<<ROWS, 256, 0, stream>>>(x1, ln2_g, ln2_b, h2);
  gemmp<2, 256><<<dim3(32, 16), 512, 163840, stream>>>(
      h2, fc_wb, fc_b, nullptr, nullptr, h3, nullptr, nullptr, nullptr, 4096, 1024);
  gemmp<1, 128><<<dim3(32, 8), 512, 131072, stream>>>(
      h3, cproj_wb, cproj_b, x1, out, nullptr, nullptr, nullptr, nullptr, 1024, 4096);
}

// Round 8
// 355.714 us; speedup vs baseline: 1.0921x; 1.0207x over previous
//
#include <hip/hip_runtime.h>

// Problem constants
#define B_   8
#define N_   1024
#define C_   1024
#define H_   16
#define P_   64
#define D_   64
#define MKV  1088      // P_ + N_
#define ROWS 8192      // B_*N_

typedef float f32x4 __attribute__((ext_vector_type(4)));
typedef __bf16 bf16x8 __attribute__((ext_vector_type(8)));
typedef unsigned short u16x8 __attribute__((ext_vector_type(8)));
typedef unsigned short u16x4 __attribute__((ext_vector_type(4)));

__device__ __forceinline__ unsigned short f2bf(float f) {
  unsigned u = __float_as_uint(f);
  u += 0x7fffu + ((u >> 16) & 1u);   // round-to-nearest-even
  return (unsigned short)(u >> 16);
}

#define GLDS16(g, l)                                                          \
  __builtin_amdgcn_global_load_lds(                                           \
      (const __attribute__((address_space(1))) void*)(g),                     \
      (__attribute__((address_space(3))) void*)(l), 16, 0, 0)

// ---------------------------------------------------------------------------
__global__ __launch_bounds__(256) void cast_bf16_k(
    const float* __restrict__ in, unsigned short* __restrict__ out, int n8) {
  int i = blockIdx.x * 256 + threadIdx.x;
  if (i >= n8) return;
  const float4 a = ((const float4*)in)[i * 2];
  const float4 c = ((const float4*)in)[i * 2 + 1];
  u16x8 o;
  o[0] = f2bf(a.x); o[1] = f2bf(a.y); o[2] = f2bf(a.z); o[3] = f2bf(a.w);
  o[4] = f2bf(c.x); o[5] = f2bf(c.y); o[6] = f2bf(c.z); o[7] = f2bf(c.w);
  *(u16x8*)(out + (size_t)i * 8) = o;
}

// ---------------------------------------------------------------------------
__global__ __launch_bounds__(256) void ln_bf16(
    const float* __restrict__ x, const float* __restrict__ g,
    const float* __restrict__ b, unsigned short* __restrict__ out) {
  const int row = blockIdx.x, t = threadIdx.x;
  const float4 v = ((const float4*)(x + (size_t)row * 1024))[t];
  float s  = v.x + v.y + v.z + v.w;
  float s2 = v.x * v.x + v.y * v.y + v.z * v.z + v.w * v.w;
#pragma unroll
  for (int m = 1; m < 64; m <<= 1) {
    s  += __shfl_xor(s, m);
    s2 += __shfl_xor(s2, m);
  }
  __shared__ float red[8];
  if ((t & 63) == 0) { red[t >> 6] = s; red[4 + (t >> 6)] = s2; }
  __syncthreads();
  s  = red[0] + red[1] + red[2] + red[3];
  s2 = red[4] + red[5] + red[6] + red[7];
  const float mu = s * (1.0f / 1024.0f);
  const float rs = rsqrtf(s2 * (1.0f / 1024.0f) - mu * mu + 1e-5f);
  const float4 gv = ((const float4*)g)[t];
  const float4 bv = ((const float4*)b)[t];
  u16x4 o;
  o[0] = f2bf((v.x - mu) * rs * gv.x + bv.x);
  o[1] = f2bf((v.y - mu) * rs * gv.y + bv.y);
  o[2] = f2bf((v.z - mu) * rs * gv.z + bv.z);
  o[3] = f2bf((v.w - mu) * rs * gv.w + bv.w);
  *(u16x4*)(out + (size_t)row * 1024 + t * 4) = o;
}

// ---------------------------------------------------------------------------
__global__ __launch_bounds__(256) void prefix_fill(
    const float* __restrict__ pk, const float* __restrict__ pv,
    unsigned short* __restrict__ Kb, unsigned short* __restrict__ Vb) {
  int i = blockIdx.x * 256 + threadIdx.x;
  int c8 = i & 127, bp = i >> 7;
  int b = bp >> 6, p = bp & 63;
  int c = c8 << 3, h = c >> 6, d = c & 63;
  size_t sidx = (size_t)bp * 1024 + c;
  size_t didx = (((size_t)(b * 16 + h)) * MKV + p) * 64 + d;
  float4 a = *(const float4*)(pk + sidx);
  float4 a2 = *(const float4*)(pk + sidx + 4);
  u16x8 o;
  o[0] = f2bf(a.x);  o[1] = f2bf(a.y);  o[2] = f2bf(a.z);  o[3] = f2bf(a.w);
  o[4] = f2bf(a2.x); o[5] = f2bf(a2.y); o[6] = f2bf(a2.z); o[7] = f2bf(a2.w);
  *(u16x8*)(Kb + didx) = o;
  a = *(const float4*)(pv + sidx);
  a2 = *(const float4*)(pv + sidx + 4);
  o[0] = f2bf(a.x);  o[1] = f2bf(a.y);  o[2] = f2bf(a.z);  o[3] = f2bf(a.w);
  o[4] = f2bf(a2.x); o[5] = f2bf(a2.y); o[6] = f2bf(a2.z); o[7] = f2bf(a2.w);
  *(u16x8*)(Vb + didx) = o;
}

// ---------------------------------------------------------------------------
__global__ __launch_bounds__(256) void transpose_v(
    const unsigned short* __restrict__ Vb, unsigned short* __restrict__ Vt) {
  __shared__ __align__(16) unsigned short Ts[64 * 66];
  const int kt = blockIdx.x, bh = blockIdx.y;
  const int t = threadIdx.x;
  const unsigned short* src = Vb + ((size_t)bh * MKV + kt * 64) * 64;
#pragma unroll
  for (int rnd = 0; rnd < 2; rnd++) {
    int chunk = rnd * 256 + t;
    int mr = chunk >> 3, d0 = (chunk & 7) << 3;
    u16x8 a = *(const u16x8*)(src + mr * 64 + d0);
#pragma unroll
    for (int j = 0; j < 8; j += 2)
      *(unsigned*)&Ts[mr * 66 + d0 + j] = (unsigned)a[j] | ((unsigned)a[j + 1] << 16);
  }
  __syncthreads();
#pragma unroll
  for (int rnd = 0; rnd < 2; rnd++) {
    int chunk = rnd * 256 + t;
    int dr = chunk >> 3, m0 = (chunk & 7) << 3;
    u16x8 o;
#pragma unroll
    for (int j = 0; j < 8; j++) o[j] = Ts[(m0 + j) * 66 + dr];
    *(u16x8*)(Vt + ((size_t)bh * 64 + dr) * MKV + kt * 64 + m0) = o;
  }
}

// ---------------------------------------------------------------------------
// GEMM "gemmp": C[M,Nd] = A[M,K] @ Bw[Nd,K]^T, bf16 in, fp32 accum.
// R6-verified staging/liveness/vmcnt (A ring of 3, B ring of 2, boundary
// vmcnt(4), one vm-drained barrier per tile) + m201-ORDERED phases:
//   {RD(p) ; STG ; BAR ; lgkmcnt(0) ; setprio MFMA(p)}  — reads issued
// BEFORE the pre-MFMA barrier so ds_read drain of phase p overlaps the MFMA
// tail of phase p-1 via cross-wave skew (the m201 62%-MfmaUtil ordering).
// All stage targets remain ring-distance >= 2 from any read; reads only ever
// target already-valid buffers, so crossing barriers is safe.
template <int EPI, int BN_>
__global__ __launch_bounds__(512, 2) void gemmp(
    const unsigned short* __restrict__ A, const unsigned short* __restrict__ Bw,
    const float* __restrict__ bias, const float* __restrict__ resid,
    float* __restrict__ outf, unsigned short* __restrict__ outb,
    unsigned short* __restrict__ qout, unsigned short* __restrict__ kout,
    unsigned short* __restrict__ vout, int Ndim, int Kdim) {
  constexpr int WN   = BN_ / 64;              // waves along N: 4 or 2
  constexpr int WMT  = (WN == 4) ? 128 : 64;  // per-wave M
  constexpr int MREP = WMT / 16;              // 8 or 4
  constexpr int ABUF = 32768;                 // 256 rows x 128B
  constexpr int BBUF = BN_ * 128;
  constexpr int BOFF = 3 * ABUF;              // 98304
  extern __shared__ __align__(16) char smem[];
  const int t = threadIdx.x;
  const int w = t >> 6, l = t & 63;
  const int wr = w / WN, wc = w % WN;
  const int q4 = l >> 4, r15 = l & 15;
  // XCD slab swizzle: gridDim.x == 32 always; xcd = fid%8 owns bm slab of 4.
  const int fid = (int)blockIdx.y * 32 + blockIdx.x;
  const int j8 = fid >> 3;
  const int bm = ((fid & 7) << 2) + (j8 & 3);
  const int bn = j8 >> 2;
  const int NS = Kdim >> 6;
  // ---- staging (pre-swizzled source, linear LDS dest = base + t*16)
  const int sr = t >> 3, scolb = (t & 7) << 4;
  const int sswz = scolb ^ ((sr & 7) << 4);
  const size_t rb = (size_t)Kdim * 2;
  const char* As0 = (const char*)A + (size_t)(bm * 256 + sr) * rb + sswz;
  const char* Bs0 = (const char*)Bw + (size_t)(bn * BN_ + sr) * rb + sswz;
  char* Adst = smem + t * 16;
  char* Bdst = smem + BOFF + t * 16;
#define STG_AH(s_, st_, h_) {                                                 \
    const int ko = (s_) << 7;                                                 \
    GLDS16(As0 + ((h_) * 128) * rb + ko,                                      \
           Adst + (st_) * ABUF + (h_) * 16384);                               \
    GLDS16(As0 + ((h_) * 128 + 64) * rb + ko,                                 \
           Adst + (st_) * ABUF + (h_) * 16384 + 8192); }
#define STG_B(s_, sb_) {                                                      \
    const int ko = (s_) << 7;                                                 \
    GLDS16(Bs0 + ko,           Bdst + (sb_) * BBUF);                          \
    GLDS16(Bs0 + 64 * rb + ko, Bdst + (sb_) * BBUF + 8192);                   \
    if (BN_ == 256) {                                                         \
      GLDS16(Bs0 + 128 * rb + ko, Bdst + (sb_) * BBUF + 16384);               \
      GLDS16(Bs0 + 192 * rb + ko, Bdst + (sb_) * BBUF + 24576); } }
  // ---- fragment read bases (swizzled ds_read)
  const int rx = (r15 & 7) << 4;
  const int c0 = (q4 << 4) ^ rx;
  const int c1 = c0 ^ 64;
  const char* arow = smem + (wr * WMT + r15) * 128;
  const char* brow = smem + BOFF + (wc * 64 + r15) * 128;
  f32x4 acc[MREP][4] = {};
#define RD_A(ms_, ck_)                                                        \
  _Pragma("unroll") for (int mf = 0; mf < 4; mf++)                            \
    af[mf] = *(const bf16x8*)(ab + ((ms_) * 64 + mf * 16) * 128 + (ck_));
#define RD_B(ck_)                                                             \
  _Pragma("unroll") for (int nf = 0; nf < 4; nf++)                            \
    bv[nf] = *(const bf16x8*)(bb + nf * 2048 + (ck_));
#define MFMA16(ms_)                                                           \
  __builtin_amdgcn_s_setprio(1);                                              \
  _Pragma("unroll") for (int mf = 0; mf < 4; mf++)                            \
  _Pragma("unroll") for (int nf = 0; nf < 4; nf++)                            \
    acc[(ms_) * 4 + mf][nf] = __builtin_amdgcn_mfma_f32_16x16x32_bf16(        \
        af[mf], bv[nf], acc[(ms_) * 4 + mf][nf], 0, 0, 0);                    \
  __builtin_amdgcn_s_setprio(0);
#define PB_PRE()                                                              \
  __builtin_amdgcn_sched_barrier(0);                                          \
  __builtin_amdgcn_s_barrier();                                               \
  asm volatile("s_waitcnt lgkmcnt(0)" ::: "memory");                          \
  __builtin_amdgcn_sched_barrier(0);
  // ---- prologue (issue order: A0, B0, A1 — same as R6/R7-verified)
  STG_AH(0, 0, 0); STG_AH(0, 0, 1);
  STG_B(0, 0);
  STG_AH(1, 1, 0); STG_AH(1, 1, 1);
  int sa = 0;
  for (int s = 0; s < NS; ++s) {
    // tile boundary: buffer cur fully staged before any read of it
    __builtin_amdgcn_sched_barrier(0);
    if (s < NS - 1) asm volatile("s_waitcnt vmcnt(4)" ::: "memory");
    else            asm volatile("s_waitcnt vmcnt(0)" ::: "memory");
    __builtin_amdgcn_s_barrier();
    __builtin_amdgcn_sched_barrier(0);
    int sa2 = sa + 2; if (sa2 >= 3) sa2 -= 3;
    const char* ab = arow + sa * ABUF;
    const char* bb = brow + (s & 1) * BBUF;
    bf16x8 af[4], bv[4];
    if constexpr (WN == 4) {
      // P1: read(ms0,k0 + B k0) | stage B(s+1) | BAR,lgkm | MFMA(ms0,k0)
      RD_A(0, c0); RD_B(c0);
      if (s + 1 < NS) STG_B(s + 1, (s + 1) & 1);
      PB_PRE();
      MFMA16(0);
      // P2: read(ms1,k0) | stage A(s+2) h0 | BAR,lgkm | MFMA(ms1,k0)
      RD_A(1, c0);
      if (s + 2 < NS) STG_AH(s + 2, sa2, 0);
      PB_PRE();
      MFMA16(1);
      // P3: read(ms0,k1 + B k1) | stage A(s+2) h1 | BAR,lgkm | MFMA(ms0,k1)
      RD_A(0, c1); RD_B(c1);
      if (s + 2 < NS) STG_AH(s + 2, sa2, 1);
      PB_PRE();
      MFMA16(0);
      // P4: read(ms1,k1) | BAR,lgkm | MFMA(ms1,k1)
      RD_A(1, c1);
      PB_PRE();
      MFMA16(1);
    } else {
      // P1: read(k0) | stage B(s+1) | BAR,lgkm | 16 MFMA
      RD_A(0, c0); RD_B(c0);
      if (s + 1 < NS) STG_B(s + 1, (s + 1) & 1);
      PB_PRE();
      MFMA16(0);
      // P2: read(k1) | stage A(s+2) | BAR,lgkm | 16 MFMA
      RD_A(0, c1); RD_B(c1);
      if (s + 2 < NS) { STG_AH(s + 2, sa2, 0); STG_AH(s + 2, sa2, 1); }
      PB_PRE();
      MFMA16(0);
    }
    sa++; if (sa == 3) sa = 0;
  }
#undef STG_AH
#undef STG_B
#undef RD_A
#undef RD_B
#undef MFMA16
#undef PB_PRE
  // ---- epilogue.  D layout: row=(l>>4)*4+reg, col=l&15 (m89/m91 verified).
  const int orow0 = bm * 256 + wr * WMT + q4 * 4;
  const int ocol0 = bn * BN_ + wc * 64 + r15;
  if (EPI == 0) {
    const int which = (bn * BN_) >> 10;  // uniform per block
#pragma unroll
    for (int mi = 0; mi < MREP; mi++)
#pragma unroll
      for (int ni = 0; ni < 4; ni++)
#pragma unroll
        for (int r = 0; r < 4; r++) {
          int m = orow0 + mi * 16 + r;
          int c = ocol0 + ni * 16;
          int cc = c & 1023;
          int h = cc >> 6, d = cc & 63;
          int b = m >> 10, n = m & 1023;
          float v = acc[mi][ni][r];
          if (which == 0)
            qout[(((size_t)(b * 16 + h)) * 1024 + n) * 64 + d] = f2bf(v * 0.125f);
          else if (which == 1)
            kout[(((size_t)(b * 16 + h)) * MKV + 64 + n) * 64 + d] = f2bf(v);
          else
            vout[(((size_t)(b * 16 + h)) * MKV + 64 + n) * 64 + d] = f2bf(v);
        }
  } else if (EPI == 1) {
#pragma unroll
    for (int mi = 0; mi < MREP; mi++)
#pragma unroll
      for (int ni = 0; ni < 4; ni++)
#pragma unroll
        for (int r = 0; r < 4; r++) {
          int c = ocol0 + ni * 16;
          size_t idx = (size_t)(orow0 + mi * 16 + r) * Ndim + c;
          outf[idx] = resid[idx] + acc[mi][ni][r] + bias[c];
        }
  } else {
#pragma unroll
    for (int mi = 0; mi < MREP; mi++)
#pragma unroll
      for (int ni = 0; ni < 4; ni++)
#pragma unroll
        for (int r = 0; r < 4; r++) {
          int c = ocol0 + ni * 16;
          size_t idx = (size_t)(orow0 + mi * 16 + r) * Ndim + c;
          float z = acc[mi][ni][r] + bias[c];
          outb[idx] = f2bf(z / (1.f + __expf(-1.702f * z)));
        }
  }
}

// ---------------------------------------------------------------------------
// Flash attention (round-3 version, verified): LDS-staged K/V double-buffered,
// swapped QK^T, 8 waves x 32 q-rows, grid (bh, qt).
__device__ __forceinline__ void online_sm(f32x4 S[4], float& m, float& lsum,
                                          f32x4 Oa[4], unsigned pw[4][2]) {
  float mx = S[0][0];
#pragma unroll
  for (int jc = 0; jc < 4; jc++)
#pragma unroll
    for (int r = 0; r < 4; r++) mx = fmaxf(mx, S[jc][r]);
  mx = fmaxf(mx, __shfl_xor(mx, 16));
  mx = fmaxf(mx, __shfl_xor(mx, 32));
  const float mn = fmaxf(m, mx);
  const float scl = __expf(m - mn);
  m = mn;
  float rs = 0.f;
#pragma unroll
  for (int jc = 0; jc < 4; jc++)
#pragma unroll
    for (int r = 0; r < 4; r++) {
      float p = __expf(S[jc][r] - mn);
      S[jc][r] = p;
      rs += p;
    }
  rs += __shfl_xor(rs, 16);
  rs += __shfl_xor(rs, 32);
  lsum = lsum * scl + rs;
#pragma unroll
  for (int db = 0; db < 4; db++)
#pragma unroll
    for (int r = 0; r < 4; r++) Oa[db][r] *= scl;
#pragma unroll
  for (int jc = 0; jc < 4; jc++) {
    pw[jc][0] = (unsigned)f2bf(S[jc][0]) | ((unsigned)f2bf(S[jc][1]) << 16);
    pw[jc][1] = (unsigned)f2bf(S[jc][2]) | ((unsigned)f2bf(S[jc][3]) << 16);
  }
}

__device__ __forceinline__ bf16x8 pexch(const unsigned pw[4][2], int kk,
                                        int src0, bool lo) {
  const unsigned a0 = pw[2 * kk][0], a1 = pw[2 * kk][1];
  const unsigned b0 = pw[2 * kk + 1][0], b1 = pw[2 * kk + 1][1];
  unsigned wA0 = (unsigned)__shfl((int)a0, src0);
  unsigned wA1 = (unsigned)__shfl((int)a1, src0);
  unsigned wB0 = (unsigned)__shfl((int)b0, src0);
  unsigned wB1 = (unsigned)__shfl((int)b1, src0);
  unsigned wA0h = (unsigned)__shfl((int)a0, src0 + 16);
  unsigned wA1h = (unsigned)__shfl((int)a1, src0 + 16);
  unsigned wB0h = (unsigned)__shfl((int)b0, src0 + 16);
  unsigned wB1h = (unsigned)__shfl((int)b1, src0 + 16);
  union { unsigned u[4]; bf16x8 v; } pf;
  pf.u[0] = lo ? wA0 : wB0;
  pf.u[1] = lo ? wA1 : wB1;
  pf.u[2] = lo ? wA0h : wB0h;
  pf.u[3] = lo ? wA1h : wB1h;
  return pf.v;
}

__global__ __launch_bounds__(512, 4) void flash_attn(
    const unsigned short* __restrict__ Qb, const unsigned short* __restrict__ Kb,
    const unsigned short* __restrict__ Vt, unsigned short* __restrict__ Ob) {
  __shared__ __align__(16) unsigned short KT[2][4096];
  __shared__ __align__(16) unsigned short VT[2][4096];
  const int t = threadIdx.x;
  const int w = t >> 6, l = t & 63;
  const int g = l >> 4, r15 = l & 15;
  const int bh = blockIdx.x, qt = blockIdx.y;
  const unsigned short* Kbh = Kb + (size_t)bh * MKV * 64;
  const unsigned short* Vbh = Vt + (size_t)bh * 64 * MKV;
  const int srow = t >> 3;
  const int scb = ((t & 7) << 4) ^ ((srow & 7) << 4);
  const char* Ksrc0 = (const char*)Kbh + srow * 128 + scb;
  const char* Vsrc0 = (const char*)Vbh + srow * (MKV * 2) + scb;
  const int qbase = qt * 256 + w * 32;
  const unsigned short* Qr0 = Qb + ((size_t)bh * 1024 + qbase + r15) * 64;
  const bf16x8 qf00 = *(const bf16x8*)(Qr0 + g * 8);
  const bf16x8 qf01 = *(const bf16x8*)(Qr0 + 32 + g * 8);
  const bf16x8 qf10 = *(const bf16x8*)(Qr0 + 16 * 64 + g * 8);
  const bf16x8 qf11 = *(const bf16x8*)(Qr0 + 16 * 64 + 32 + g * 8);
  f32x4 Oa0[4] = {}, Oa1[4] = {};
  float m0 = -1e30f, l0 = 0.f, m1 = -1e30f, l1 = 0.f;
  const int src0 = r15 + ((l & 16) << 1);
  const bool lo = (l < 32);
  const int rx = (r15 & 7) << 4;
  GLDS16(Ksrc0, &KT[0][t * 8]);
  GLDS16(Vsrc0, &VT[0][t * 8]);
  __syncthreads();
  int cur = 0;
  for (int kt = 0; kt < 17; ++kt) {
    if (kt < 16) {
      GLDS16(Ksrc0 + (kt + 1) * 8192, &KT[cur ^ 1][t * 8]);
      GLDS16(Vsrc0 + (kt + 1) * 128, &VT[cur ^ 1][t * 8]);
    }
    const char* Kl = (const char*)&KT[cur][0];
    const char* Vl = (const char*)&VT[cur][0];
    f32x4 S0[4], S1[4];
#pragma unroll
    for (int jc = 0; jc < 4; jc++) {
      const char* kr = Kl + jc * 2048 + r15 * 128;
      bf16x8 k0 = *(const bf16x8*)(kr + ((g * 16) ^ rx));
      bf16x8 k1 = *(const bf16x8*)(kr + ((64 + g * 16) ^ rx));
      f32x4 a0 = {}, a1 = {};
      a0 = __builtin_amdgcn_mfma_f32_16x16x32_bf16(k0, qf00, a0, 0, 0, 0);
      a0 = __builtin_amdgcn_mfma_f32_16x16x32_bf16(k1, qf01, a0, 0, 0, 0);
      a1 = __builtin_amdgcn_mfma_f32_16x16x32_bf16(k0, qf10, a1, 0, 0, 0);
      a1 = __builtin_amdgcn_mfma_f32_16x16x32_bf16(k1, qf11, a1, 0, 0, 0);
      S0[jc] = a0; S1[jc] = a1;
    }
    unsigned pw0[4][2], pw1[4][2];
    online_sm(S0, m0, l0, Oa0, pw0);
    online_sm(S1, m1, l1, Oa1, pw1);
#pragma unroll
    for (int kk = 0; kk < 2; kk++) {
      bf16x8 pf0 = pexch(pw0, kk, src0, lo);
      bf16x8 pf1 = pexch(pw1, kk, src0, lo);
#pragma unroll
      for (int db = 0; db < 4; db++) {
        bf16x8 va = *(const bf16x8*)(Vl + db * 2048 + r15 * 128 +
                                     ((kk * 64 + g * 16) ^ rx));
        Oa0[db] = __builtin_amdgcn_mfma_f32_16x16x32_bf16(va, pf0, Oa0[db], 0, 0, 0);
        Oa1[db] = __builtin_amdgcn_mfma_f32_16x16x32_bf16(va, pf1, Oa1[db], 0, 0, 0);
      }
    }
    __syncthreads();
    cur ^= 1;
  }
  const int b = bh >> 4, h = bh & 15;
  const float i0 = 1.f / l0, i1 = 1.f / l1;
  const int n0 = qbase + r15;
#pragma unroll
  for (int db = 0; db < 4; db++) {
    u16x4 o;
#pragma unroll
    for (int r = 0; r < 4; r++) o[r] = f2bf(Oa0[db][r] * i0);
    *(u16x4*)(Ob + ((size_t)b * 1024 + n0) * 1024 + h * 64 + db * 16 + g * 4) = o;
#pragma unroll
    for (int r = 0; r < 4; r++) o[r] = f2bf(Oa1[db][r] * i1);
    *(u16x4*)(Ob + ((size_t)b * 1024 + n0 + 16) * 1024 + h * 64 + db * 16 + g * 4) = o;
  }
}

// ---------------------------------------------------------------------------
extern "C" void kernel_launch(void* const* d_in, const int* in_sizes, int n_in,
                              void* d_out, int out_size, void* d_ws, size_t ws_size,
                              hipStream_t stream) {
  const float* x       = (const float*)d_in[0];
  const float* pk      = (const float*)d_in[1];
  const float* pv      = (const float*)d_in[2];
  const float* qkv_w   = (const float*)d_in[3];
  const float* proj_w  = (const float*)d_in[4];
  const float* proj_b  = (const float*)d_in[5];
  const float* ln1_g   = (const float*)d_in[6];
  const float* ln1_b   = (const float*)d_in[7];
  const float* ln2_g   = (const float*)d_in[8];
  const float* ln2_b   = (const float*)d_in[9];
  const float* fc_w    = (const float*)d_in[10];
  const float* fc_b    = (const float*)d_in[11];
  const float* cproj_w = (const float*)d_in[12];
  const float* cproj_b = (const float*)d_in[13];
  float* out = (float*)d_out;
  char* ws = (char*)d_ws;

  unsigned short* qkv_wb   = (unsigned short*)(ws + 0);          // 6291456
  unsigned short* proj_wb  = (unsigned short*)(ws + 6291456);    // 2097152
  unsigned short* fc_wb    = (unsigned short*)(ws + 8388608);    // 8388608
  unsigned short* cproj_wb = (unsigned short*)(ws + 16777216);   // 8388608
  float*          x1       = (float*)(ws + 25165824);            // 33554432
  unsigned short* h1       = (unsigned short*)(ws + 58720256);   // 16777216
  unsigned short* o_b      = h1;                                 // alias (h1 dead)
  unsigned short* h2       = (unsigned short*)(ws + 75497472);   // 16777216
  unsigned short* q_buf    = (unsigned short*)(ws + 92274688);   // 16777216
  unsigned short* Kb       = (unsigned short*)(ws + 109051904);  // 17825792
  unsigned short* Vb       = (unsigned short*)(ws + 126877696);  // 17825792
  unsigned short* Vt       = (unsigned short*)(ws + 144703488);  // 17825792
  unsigned short* h3       = (unsigned short*)(ws + 92274688);   // alias (dead)
  if (ws_size < 162529280u) return;

  // allow big dynamic LDS (idempotent host-side calls — capture-safe)
  (void)hipFuncSetAttribute((const void*)gemmp<0, 256>,
      hipFuncAttributeMaxDynamicSharedMemorySize, 163840);
  (void)hipFuncSetAttribute((const void*)gemmp<2, 256>,
      hipFuncAttributeMaxDynamicSharedMemorySize, 163840);
  (void)hipFuncSetAttribute((const void*)gemmp<1, 128>,
      hipFuncAttributeMaxDynamicSharedMemorySize, 131072);

  cast_bf16_k<<<1536, 256, 0, stream>>>(qkv_w, qkv_wb, 393216);
  cast_bf16_k<<<512, 256, 0, stream>>>(proj_w, proj_wb, 131072);
  cast_bf16_k<<<2048, 256, 0, stream>>>(fc_w, fc_wb, 524288);
  cast_bf16_k<<<2048, 256, 0, stream>>>(cproj_w, cproj_wb, 524288);
  ln_bf16<<<ROWS, 256, 0, stream>>>(x, ln1_g, ln1_b, h1);
  prefix_fill<<<256, 256, 0, stream>>>(pk, pv, Kb, Vb);
  gemmp<0, 256><<<dim3(32, 12), 512, 163840, stream>>>(
      h1, qkv_wb, nullptr, nullptr, nullptr, nullptr, q_buf, Kb, Vb, 3072, 1024);
  transpose_v<<<dim3(17, 128), 256, 0, stream>>>(Vb, Vt);
  flash_attn<<<dim3(128, 4), 512, 0, stream>>>(q_buf, Kb, Vt, o_b);
  gemmp<1, 128><<<dim3(32, 8), 512, 131072, stream>>>(
      o_b, proj_wb, proj_b, x, x1, nullptr, nullptr, nullptr, nullptr, 1024, 1024);
  ln_bf16<<<ROWS, 256, 0, stream>>>(x1, ln2_g, ln2_b, h2);
  gemmp<2, 256><<<dim3(32, 16), 512, 163840, stream>>>(
      h2, fc_wb, fc_b, nullptr, nullptr, h3, nullptr, nullptr, nullptr, 4096, 1024);
  gemmp<1, 128><<<dim3(32, 8), 512, 131072, stream>>>(
      h3, cproj_wb, cproj_b, x1, out, nullptr, nullptr, nullptr, nullptr, 1024, 4096);
}